// Round 11
// baseline (104.569 us; speedup 1.0000x reference)
//
#include <hip/hip_runtime.h>
#include <hip/hip_bf16.h>
#include <math.h>

#define BB 2
#define TT 2048
#define DD 768
#define HH 12
#define ND 64
#define MM (BB*TT)   // 4096

typedef __attribute__((ext_vector_type(8))) short bf16x8;
typedef __attribute__((ext_vector_type(4))) float f32x4;
typedef __attribute__((ext_vector_type(16))) float f32x16;

__device__ __forceinline__ float bf2f(ushort u) {
    union { unsigned int i; float f; } v; v.i = ((unsigned int)u) << 16; return v.f;
}
__device__ __forceinline__ ushort f2bf(float f) {
    union { float f; unsigned int i; } v; v.f = f;
    unsigned int r = v.i + 0x7FFF + ((v.i >> 16) & 1);   // RNE
    return (ushort)(r >> 16);
}

// async global->LDS, 16B per lane. LDS base must be wave-uniform; HW adds lane*16.
__device__ __forceinline__ void cp16(void* lds, const void* g) {
    __builtin_amdgcn_global_load_lds(
        (const __attribute__((address_space(1))) void*)g,
        (__attribute__((address_space(3))) void*)lds, 16, 0, 0);
}

__device__ __forceinline__ float fexp2(float x) {
    float r; asm("v_exp_f32 %0, %1" : "=v"(r) : "v"(x)); return r;
}
__device__ __forceinline__ unsigned int pk_bf16(float a, float b) {
    unsigned int r; asm("v_cvt_pk_bf16_f32 %0, %1, %2" : "=v"(r) : "v"(a), "v"(b)); return r;
}

__device__ __forceinline__ void plswap(unsigned int& a, unsigned int& b) {
#if __has_builtin(__builtin_amdgcn_permlane32_swap)
    auto r = __builtin_amdgcn_permlane32_swap(a, b, false, false);
    a = r[0]; b = r[1];
#else
    unsigned int sa = __shfl_xor((int)a, 32), sb = __shfl_xor((int)b, 32);
    bool hi = (threadIdx.x & 63) >= 32;
    unsigned int na = hi ? sb : a, nb = hi ? b : sa;
    a = na; b = nb;
#endif
}
__device__ __forceinline__ float partner32(float x, int hi) {
#if __has_builtin(__builtin_amdgcn_permlane32_swap)
    unsigned int u = __float_as_uint(x);
    auto r = __builtin_amdgcn_permlane32_swap(u, u, false, false);
    return __uint_as_float(hi ? r[0] : r[1]);
#else
    return __shfl_xor(x, 32);
#endif
}

#define QSCALE 0.18033688011112043f   // 0.125 * log2(e)

// ---------------------------------------------------------------------------
// Combined conversion kernel (one launch):
//   z = 0..2 : q/k/v f32 -> bf16, grid-stride over x
//   z = 3..6 : wq/wk/wv/wo f32 [k][n] -> bf16 transposed [n][k] (x < 144)
// ---------------------------------------------------------------------------
__global__ __launch_bounds__(256) void conv_all(
    const float* __restrict__ x0, const float* __restrict__ x1, const float* __restrict__ x2,
    ushort* __restrict__ o0, ushort* __restrict__ o1, ushort* __restrict__ o2,
    const float* __restrict__ w0, const float* __restrict__ w1,
    const float* __restrict__ w2, const float* __restrict__ w3,
    ushort* __restrict__ t0, ushort* __restrict__ t1,
    ushort* __restrict__ t2, ushort* __restrict__ t3)
{
    const int z = blockIdx.z;
    if (z < 3) {
        const float* x = z == 0 ? x0 : (z == 1 ? x1 : x2);
        ushort* o = z == 0 ? o0 : (z == 1 ? o1 : o2);
        const int total4 = MM * DD / 4;
        for (int i = blockIdx.x * 256 + threadIdx.x; i < total4; i += gridDim.x * 256) {
            float4 v = *(const float4*)&x[i * 4];
            ushort4 r;
            r.x = f2bf(v.x); r.y = f2bf(v.y); r.z = f2bf(v.z); r.w = f2bf(v.w);
            *(ushort4*)&o[i * 4] = r;
        }
    } else {
        if (blockIdx.x >= (DD / 64) * (DD / 64)) return;
        __shared__ ushort tile[64][72];
        const int zz = z - 3;
        const float* w = zz == 0 ? w0 : zz == 1 ? w1 : zz == 2 ? w2 : w3;
        ushort* o = zz == 0 ? t0 : zz == 1 ? t1 : zz == 2 ? t2 : t3;
        const int n0 = (blockIdx.x % (DD / 64)) * 64;
        const int k0 = (blockIdx.x / (DD / 64)) * 64;
        #pragma unroll
        for (int it = 0; it < 4; ++it) {
            int e = (threadIdx.x + it * 256) * 4;
            int r = e >> 6, c = e & 63;
            float4 v = *(const float4*)&w[(size_t)(k0 + r) * DD + n0 + c];
            tile[c + 0][r] = f2bf(v.x);
            tile[c + 1][r] = f2bf(v.y);
            tile[c + 2][r] = f2bf(v.z);
            tile[c + 3][r] = f2bf(v.w);
        }
        __syncthreads();
        #pragma unroll
        for (int it = 0; it < 4; ++it) {
            int e = (threadIdx.x + it * 256) * 4;
            int nr = e >> 6, kc = e & 63;
            ushort4 r4;
            r4.x = tile[nr][kc + 0];
            r4.y = tile[nr][kc + 1];
            r4.z = tile[nr][kc + 2];
            r4.w = tile[nr][kc + 3];
            *(ushort4*)&o[(size_t)(n0 + nr) * DD + k0 + kc] = r4;
        }
    }
}

// ---------------------------------------------------------------------------
// MFMA GEMM: A[M][K=768] bf16 x WT[N][K] bf16. Tile TM x TN (128x96: 17.8
// staged-bytes/kFLOP vs 23 at 128x64 -- stage-bound regime, m233), 4 waves
// 2x2, BK=64 (128B rows), XOR-swizzled LDS (byte ^= (row&7)<<4), coalesced
// in-row pre-swizzled cp16 source. 2-buffer __syncthreads loop.
// MODE 0: rope>=0 -> bf16 head layout [B,H,T,ND] + bias (+fused RoPE);
//         rope==-1 -> bf16 transposed layout [B][n][T] (= [B,H,ND,T]) + bias
//                     (V path: emits V^T directly; tile may span heads since
//                     (b*H+h)*ND+d == b*D+n)
// MODE 1: f32 flat [M][N], no bias.
// ---------------------------------------------------------------------------
struct GArgs { const ushort* x; const ushort* wt; const float* bias; void* out;
               const float* cT; const float* sT; int rope; };

template<int MODE, int TM, int TN>
__global__ __launch_bounds__(256) void gemm_bf16(GArgs a0, GArgs a1, GArgs a2)
{
    constexpr int WM = TM / 2, WN = TN / 2;
    constexpr int MF = WM / 16, NF = WN / 16;
    constexpr int ABYTES = TM * 128;          // A region bytes (128B per row)
    constexpr int BUFB = (TM + TN) * 128;     // bytes per buffer (A then B)
    constexpr int NPASS = BUFB / 4096;        // staging passes (4KB per pass)
    constexpr int NK = DD / 64;               // 12 K-iterations
    __shared__ __align__(16) ushort S[2][BUFB / 2];
    GArgs ga = (blockIdx.z == 0) ? a0 : (blockIdx.z == 1 ? a1 : a2);
    const int tid = threadIdx.x;
    const int w = tid >> 6, l = tid & 63;
    const int wr = w >> 1, wc = w & 1;
    const int n0 = blockIdx.x * TN, m0 = blockIdx.y * TM;

    f32x4 acc[MF][NF] = {};

    auto stage = [&](int buf, int k0) {
        #pragma unroll
        for (int it = 0; it < NPASS; ++it) {
            const int ob = it * 4096 + w * 1024;       // wave-uniform chunk base
            const int o = ob + l * 16;
            if (ob < ABYTES) {
                const int row = o >> 7, inner = o & 127;
                cp16((char*)&S[buf][0] + ob,
                     (const char*)ga.x + (size_t)(m0 + row) * (DD * 2) + k0 * 2 +
                     (inner ^ ((row & 7) << 4)));
            } else {
                const int o2 = o - ABYTES;
                const int row = o2 >> 7, inner = o2 & 127;
                cp16((char*)&S[buf][0] + ob,
                     (const char*)ga.wt + (size_t)(n0 + row) * (DD * 2) + k0 * 2 +
                     (inner ^ ((row & 7) << 4)));
            }
        }
    };

    stage(0, 0);
    __syncthreads();
    const int lq = l >> 4, lr = l & 15;
    for (int t = 0; t < NK; ++t) {
        const int cur = t & 1;
        if (t + 1 < NK) stage(cur ^ 1, (t + 1) * 64);
        const char* ab = (const char*)&S[cur][0];
        #pragma unroll
        for (int kc = 0; kc < 2; ++kc) {
            const int kb = kc * 64 + lq * 16;
            bf16x8 af[MF], bfr[NF];
            #pragma unroll
            for (int i = 0; i < MF; ++i) {
                const int row = WM * wr + 16 * i + lr;
                af[i] = *(const bf16x8*)(ab + row * 128 + (kb ^ ((row & 7) << 4)));
            }
            #pragma unroll
            for (int j = 0; j < NF; ++j) {
                const int row = WN * wc + 16 * j + lr;
                bfr[j] = *(const bf16x8*)(ab + ABYTES + row * 128 + (kb ^ ((row & 7) << 4)));
            }
            __builtin_amdgcn_s_setprio(1);
            #pragma unroll
            for (int i = 0; i < MF; ++i)
                #pragma unroll
                for (int j = 0; j < NF; ++j)
                    acc[i][j] = __builtin_amdgcn_mfma_f32_16x16x32_bf16(af[i], bfr[j], acc[i][j], 0, 0, 0);
            __builtin_amdgcn_s_setprio(0);
        }
        __syncthreads();
    }

    if (MODE == 0 && ga.rope == -1) {
        // ---- transposed epilogue (V^T): out[b][n][t], n = h*64+d ----
        ushort* tl = (ushort*)&S[0][0];   // [TN][TM + 8] padded bf16 tile
        #pragma unroll
        for (int i = 0; i < MF; ++i) {
            #pragma unroll
            for (int j = 0; j < NF; ++j) {
                #pragma unroll
                for (int r = 0; r < 4; ++r) {
                    const int ml = WM * wr + 16 * i + (l >> 4) * 4 + r;
                    const int nl = WN * wc + 16 * j + (l & 15);
                    tl[nl * (TM + 8) + ml] = f2bf(acc[i][j][r] + ga.bias[n0 + nl]);
                }
            }
        }
        __syncthreads();
        const int b = m0 >> 11, t0b = m0 & 2047;
        ushort* base = (ushort*)ga.out + ((size_t)(b * DD + n0)) * TT + t0b;
        #pragma unroll
        for (int it = 0; it < TM * TN / (256 * 8); ++it) {
            const int slot = tid + it * 256;
            const int d = slot / (TM / 8), c = (slot % (TM / 8)) * 8;
            bf16x8 v = *(const bf16x8*)&tl[d * (TM + 8) + c];
            *(bf16x8*)&base[(size_t)d * TT + c] = v;
        }
        return;
    }

    #pragma unroll
    for (int i = 0; i < MF; ++i) {
        #pragma unroll
        for (int j = 0; j < NF; ++j) {
            #pragma unroll
            for (int r = 0; r < 4; ++r) {
                const int m = m0 + WM * wr + 16 * i + (l >> 4) * 4 + r;
                const int n = n0 + WN * wc + 16 * j + (l & 15);
                float v = acc[i][j][r];
                if (MODE == 0) {
                    v += ga.bias[n];
                    const int tt = m & 2047;
                    if (ga.rope > 0) {
                        const int d = n & 63;
                        const float c = ga.cT[tt * 32 + (d >> 1)];
                        const float s = ga.sT[tt * 32 + (d >> 1)];
                        const float pv = __shfl_xor(v, 1);
                        v = (n & 1) ? (pv * s + v * c) : (v * c - pv * s);
                        if (ga.rope == 2) v *= QSCALE;
                    }
                    const int b = m >> 11;
                    const int h = n >> 6, d = n & 63;
                    ((ushort*)ga.out)[((size_t)(b * HH + h) * TT + tt) * ND + d] = f2bf(v);
                } else {
                    ((float*)ga.out)[(size_t)m * DD + n] = v;
                }
            }
        }
    }
}

// ---------------------------------------------------------------------------
// MFMA flash attention, 32x32 swapped-operand + in-block KV-split + balanced
// static schedule. 1D grid of NTASK=384 tasks (16 qblk x 24 bh).
// ---------------------------------------------------------------------------
#define NQB (TT/128)        // 16
#define NBH (BB*HH)         // 24
#define NTASK (NQB*NBH)     // 384
#define NCU 256

__global__ __launch_bounds__(512) void attn_mfma4(const ushort* __restrict__ Qh,
                                                  const ushort* __restrict__ Kh,
                                                  const ushort* __restrict__ VhT,
                                                  ushort* __restrict__ Op)
{
    __shared__ __align__(16) ushort Ks[2][2][4096];   // [kvhalf][buf][64kv x 64d] swizzled
    __shared__ __align__(16) ushort Vs[2][2][4096];   // [kvhalf][buf][64d x 64kv] swizzled
    const int tid = threadIdx.x;
    const int w = tid >> 6, l = tid & 63;
    const int lq = l & 31, hi = l >> 5;
    const int qs = w & 3;                 // q subgroup (32 rows)
    const int kvh = w >> 2;               // kv half

    const int n = blockIdx.x;
    const int r_ = (n < NCU) ? n : (NTASK - 1 + NCU - n);
    const int qblk = (NQB - 1) - r_ / NBH;
    const int bh = r_ % NBH;

    const int q0 = qblk * 128;
    const int q0w = q0 + qs * 32;
    const int qg = q0w + lq;              // this lane's q row
    const int ntH = qblk + 1;             // kv tiles per half
    const int kvbase = kvh * ntH * 64;

    const ushort* Qg = Qh + ((size_t)bh * TT + q0w) * ND;
    const ushort* Kg = Kh + (size_t)bh * TT * ND;
    const ushort* Vg = VhT + (size_t)bh * ND * TT;

    // Q fragments from global (B-operand: lane holds q row lq, d = ks*16+hi*8+e)
    bf16x8 qf[4];
    #pragma unroll
    for (int ks = 0; ks < 4; ++ks)
        qf[ks] = *(const bf16x8*)((const char*)Qg + lq * 128 + ks * 32 + hi * 16);

    auto stageKV = [&](int buf, int kv0) {
        #pragma unroll
        for (int it = 0; it < 2; ++it) {
            int o = it * 4096 + qs * 1024 + l * 16;
            int row = o >> 7, inner = o & 127;
            int swz = inner ^ ((row & 7) << 4);
            cp16((char*)&Ks[kvh][buf][0] + it * 4096 + qs * 1024,
                 (const char*)Kg + (size_t)(kv0 + row) * 128 + swz);
            cp16((char*)&Vs[kvh][buf][0] + it * 4096 + qs * 1024,
                 (const char*)Vg + (size_t)row * (TT * 2) + kv0 * 2 + swz);
        }
    };

    float m = -1e30f, lsum = 0.f;
    f32x16 o0 = {}, o1 = {};

    stageKV(0, kvbase);
    __syncthreads();
    for (int t = 0; t < ntH; ++t) {
        const int cur = t & 1;
        if (t + 1 < ntH) stageKV(cur ^ 1, kvbase + (t + 1) * 64);
        const char* kb = (const char*)&Ks[kvh][cur][0];
        const char* vb = (const char*)&Vs[kvh][cur][0];
        const int kvt = kvbase + t * 64;

        if (kvt <= q0w + 31) {
            const bool have1 = (kvt + 32 <= q0w + 31);   // wave-uniform

            // S^T[kv][q]: both 32-kv subtiles
            f32x16 st0 = {}, st1 = {};
            __builtin_amdgcn_s_setprio(1);
            #pragma unroll
            for (int ks = 0; ks < 4; ++ks) {
                bf16x8 kf = *(const bf16x8*)(kb + lq * 128 +
                                             ((ks * 32 + hi * 16) ^ ((lq & 7) << 4)));
                st0 = __builtin_amdgcn_mfma_f32_32x32x16_bf16(kf, qf[ks], st0, 0, 0, 0);
            }
            if (have1) {
                #pragma unroll
                for (int ks = 0; ks < 4; ++ks) {
                    bf16x8 kf = *(const bf16x8*)(kb + (32 + lq) * 128 +
                                                 ((ks * 32 + hi * 16) ^ ((lq & 7) << 4)));
                    st1 = __builtin_amdgcn_mfma_f32_32x32x16_bf16(kf, qf[ks], st1, 0, 0, 0);
                }
            }
            __builtin_amdgcn_s_setprio(0);

            // causal mask + tile max over all 64 kv (one chain per tile)
            float tm = -1e30f;
            if (kvt + 31 > q0w) {
                #pragma unroll
                for (int r = 0; r < 16; ++r) {
                    const int kvg = kvt + (r & 3) + 8 * (r >> 2) + 4 * hi;
                    float x = (kvg <= qg) ? st0[r] : -1e30f;
                    st0[r] = x;
                    tm = fmaxf(tm, x);
                }
            } else {
                #pragma unroll
                for (int r = 0; r < 16; ++r) tm = fmaxf(tm, st0[r]);
            }
            if (have1) {
                if (kvt + 63 > q0w) {
                    #pragma unroll
                    for (int r = 0; r < 16; ++r) {
                        const int kvg = kvt + 32 + (r & 3) + 8 * (r >> 2) + 4 * hi;
                        float x = (kvg <= qg) ? st1[r] : -1e30f;
                        st1[r] = x;
                        tm = fmaxf(tm, x);
                    }
                } else {
                    #pragma unroll
                    for (int r = 0; r < 16; ++r) tm = fmaxf(tm, st1[r]);
                }
            }
            tm = fmaxf(tm, partner32(tm, hi));

            // defer-max (T13)
            const bool defer = __all(tm <= m + 11.5f);
            float alpha = 1.f;
            if (!defer) {
                const float nm = fmaxf(m, tm);
                alpha = fexp2(m - nm);
                m = nm;
            }

            // P = exp2(S - m), pack to bf16 pairs, tree rowsum
            float ps[16];
            unsigned int pkA[8], pkB[8];
            #pragma unroll
            for (int i = 0; i < 8; ++i) {
                const float p0 = fexp2(st0[2 * i + 0] - m);
                const float p1 = fexp2(st0[2 * i + 1] - m);
                pkA[i] = pk_bf16(p0, p1);
                ps[i] = p0 + p1;
            }
            if (have1) {
                #pragma unroll
                for (int i = 0; i < 8; ++i) {
                    const float p0 = fexp2(st1[2 * i + 0] - m);
                    const float p1 = fexp2(st1[2 * i + 1] - m);
                    pkB[i] = pk_bf16(p0, p1);
                    ps[8 + i] = p0 + p1;
                }
            } else {
                #pragma unroll
                for (int i = 0; i < 8; ++i) { pkB[i] = 0; ps[8 + i] = 0.f; }
            }
            const float t0s = (ps[0] + ps[1]) + (ps[2] + ps[3]);
            const float t1s = (ps[4] + ps[5]) + (ps[6] + ps[7]);
            const float t2s = (ps[8] + ps[9]) + (ps[10] + ps[11]);
            const float t3s = (ps[12] + ps[13]) + (ps[14] + ps[15]);
            float rs = (t0s + t1s) + (t2s + t3s);
            rs += partner32(rs, hi);
            lsum = lsum * alpha + rs;

            // rearrange into PV B-fragments
            plswap(pkA[0], pkA[2]); plswap(pkA[1], pkA[3]);
            plswap(pkA[4], pkA[6]); plswap(pkA[5], pkA[7]);
            if (have1) {
                plswap(pkB[0], pkB[2]); plswap(pkB[1], pkB[3]);
                plswap(pkB[4], pkB[6]); plswap(pkB[5], pkB[7]);
            }
            union { unsigned int u[4]; bf16x8 v; } pa0, pa1, pa2, pa3;
            pa0.u[0] = pkA[0]; pa0.u[1] = pkA[1]; pa0.u[2] = pkA[2]; pa0.u[3] = pkA[3];
            pa1.u[0] = pkA[4]; pa1.u[1] = pkA[5]; pa1.u[2] = pkA[6]; pa1.u[3] = pkA[7];
            pa2.u[0] = pkB[0]; pa2.u[1] = pkB[1]; pa2.u[2] = pkB[2]; pa2.u[3] = pkB[3];
            pa3.u[0] = pkB[4]; pa3.u[1] = pkB[5]; pa3.u[2] = pkB[6]; pa3.u[3] = pkB[7];

            if (!defer) {
                #pragma unroll
                for (int r = 0; r < 16; ++r) { o0[r] *= alpha; o1[r] *= alpha; }
            }

            // O^T += V^T * P
            __builtin_amdgcn_s_setprio(1);
            #pragma unroll
            for (int sl = 0; sl < 2; ++sl) {
                const bf16x8 pf = sl == 0 ? pa0.v : pa1.v;
                const int cb = sl * 32 + hi * 16;
                bf16x8 va = *(const bf16x8*)(vb + lq * 128 + (cb ^ ((lq & 7) << 4)));
                bf16x8 vc = *(const bf16x8*)(vb + (lq + 32) * 128 + (cb ^ ((lq & 7) << 4)));
                o0 = __builtin_amdgcn_mfma_f32_32x32x16_bf16(va, pf, o0, 0, 0, 0);
                o1 = __builtin_amdgcn_mfma_f32_32x32x16_bf16(vc, pf, o1, 0, 0, 0);
            }
            if (have1) {
                #pragma unroll
                for (int sl = 0; sl < 2; ++sl) {
                    const bf16x8 pf = sl == 0 ? pa2.v : pa3.v;
                    const int cb = 64 + sl * 32 + hi * 16;
                    bf16x8 va = *(const bf16x8*)(vb + lq * 128 + (cb ^ ((lq & 7) << 4)));
                    bf16x8 vc = *(const bf16x8*)(vb + (lq + 32) * 128 + (cb ^ ((lq & 7) << 4)));
                    o0 = __builtin_amdgcn_mfma_f32_32x32x16_bf16(va, pf, o0, 0, 0, 0);
                    o1 = __builtin_amdgcn_mfma_f32_32x32x16_bf16(vc, pf, o1, 0, 0, 0);
                }
            }
            __builtin_amdgcn_s_setprio(0);
        }
        __syncthreads();
    }

    // ---- merge kv halves through LDS ----
    float* xO  = (float*)&Ks[0][0][0];    // 4 regions x 8KB = 32KB ([reg][lane])
    float* xML = (float*)&Vs[0][0][0];    // m,l per q-sub
    if (kvh == 1) {
        float* dst = xO + qs * 2048;
        #pragma unroll
        for (int r = 0; r < 16; ++r) {
            dst[r * 64 + l] = o0[r];
            dst[(r + 16) * 64 + l] = o1[r];
        }
        if (hi == 0) { xML[qs * 64 + lq] = m; xML[qs * 64 + 32 + lq] = lsum; }
    }
    __syncthreads();
    if (kvh == 0) {
        const float* src = xO + qs * 2048;
        const float m1 = xML[qs * 64 + lq];
        const float l1 = xML[qs * 64 + 32 + lq];
        const float ms = fmaxf(m, m1);
        const float a0 = fexp2(m - ms), a1 = fexp2(m1 - ms);
        const float inv = 1.0f / (lsum * a0 + l1 * a1);
        const int b = bh / HH, h = bh % HH;
        ushort* dst = Op + ((size_t)(b * TT + qg)) * DD + h * ND;
        #pragma unroll
        for (int g = 0; g < 4; ++g) {
            ushort4 w0, w1;
            w0.x = f2bf((o0[4 * g + 0] * a0 + src[(4 * g + 0) * 64 + l] * a1) * inv);
            w0.y = f2bf((o0[4 * g + 1] * a0 + src[(4 * g + 1) * 64 + l] * a1) * inv);
            w0.z = f2bf((o0[4 * g + 2] * a0 + src[(4 * g + 2) * 64 + l] * a1) * inv);
            w0.w = f2bf((o0[4 * g + 3] * a0 + src[(4 * g + 3) * 64 + l] * a1) * inv);
            *(ushort4*)&dst[8 * g + 4 * hi] = w0;
            w1.x = f2bf((o1[4 * g + 0] * a0 + src[(16 + 4 * g + 0) * 64 + l] * a1) * inv);
            w1.y = f2bf((o1[4 * g + 1] * a0 + src[(16 + 4 * g + 1) * 64 + l] * a1) * inv);
            w1.z = f2bf((o1[4 * g + 2] * a0 + src[(16 + 4 * g + 2) * 64 + l] * a1) * inv);
            w1.w = f2bf((o1[4 * g + 3] * a0 + src[(16 + 4 * g + 3) * 64 + l] * a1) * inv);
            *(ushort4*)&dst[32 + 8 * g + 4 * hi] = w1;
        }
    }
}

// ---------------------------------------------------------------------------
extern "C" void kernel_launch(void* const* d_in, const int* in_sizes, int n_in,
                              void* d_out, int out_size, void* d_ws, size_t ws_size,
                              hipStream_t stream)
{
    const float* q  = (const float*)d_in[0];
    const float* k  = (const float*)d_in[1];
    const float* v  = (const float*)d_in[2];
    const float* wq = (const float*)d_in[4];
    const float* bq = (const float*)d_in[5];
    const float* wk = (const float*)d_in[6];
    const float* bk = (const float*)d_in[7];
    const float* wv = (const float*)d_in[8];
    const float* bv = (const float*)d_in[9];
    const float* wo = (const float*)d_in[10];
    const float* fc = (const float*)d_in[11];
    const float* fs = (const float*)d_in[12];
    float* out = (float*)d_out;

    ushort* qB  = (ushort*)d_ws;           // [M][D] bf16
    ushort* kB  = qB  + (size_t)MM * DD;
    ushort* vB  = kB  + (size_t)MM * DD;
    ushort* wqT = vB  + (size_t)MM * DD;   // [n][k] bf16
    ushort* wkT = wqT + (size_t)DD * DD;
    ushort* wvT = wkT + (size_t)DD * DD;
    ushort* woT = wvT + (size_t)DD * DD;
    ushort* Qh  = woT + (size_t)DD * DD;   // [B,H,T,ND] bf16
    ushort* Kh  = Qh  + (size_t)MM * DD;
    ushort* VhT = Kh  + (size_t)MM * DD;   // [B,H,ND,T] bf16 (direct from V-GEMM)
    ushort* Op  = qB;                      // alias: qB dead after QKV GEMM

    conv_all<<<dim3(2048, 1, 7), 256, 0, stream>>>(q, k, v, qB, kB, vB,
                                                   wq, wk, wv, wo, wqT, wkT, wvT, woT);

    GArgs aq{qB, wqT, bq, (void*)Qh, fc, fs, 2};
    GArgs ak{kB, wkT, bk, (void*)Kh, fc, fs, 1};
    GArgs av{vB, wvT, bv, (void*)VhT, nullptr, nullptr, -1};   // V^T direct
    gemm_bf16<0, 128, 96><<<dim3(DD / 96, MM / 128, 3), 256, 0, stream>>>(aq, ak, av);

    attn_mfma4<<<dim3(NTASK), 512, 0, stream>>>(Qh, Kh, VhT, Op);

    GArgs ao{Op, woT, nullptr, (void*)out, nullptr, nullptr, 0};
    gemm_bf16<1, 128, 96><<<dim3(DD / 96, MM / 128, 1), 256, 0, stream>>>(ao, ao, ao);
}

// Round 12
// 95.558 us; speedup vs baseline: 1.0943x; 1.0943x over previous
//
#include <hip/hip_runtime.h>
#include <hip/hip_bf16.h>
#include <math.h>

#define BB 2
#define TT 2048
#define DD 768
#define HH 12
#define ND 64
#define MM (BB*TT)   // 4096

typedef __attribute__((ext_vector_type(8))) short bf16x8;
typedef __attribute__((ext_vector_type(4))) float f32x4;
typedef __attribute__((ext_vector_type(16))) float f32x16;

__device__ __forceinline__ float bf2f(ushort u) {
    union { unsigned int i; float f; } v; v.i = ((unsigned int)u) << 16; return v.f;
}
__device__ __forceinline__ ushort f2bf(float f) {
    union { float f; unsigned int i; } v; v.f = f;
    unsigned int r = v.i + 0x7FFF + ((v.i >> 16) & 1);   // RNE
    return (ushort)(r >> 16);
}

// async global->LDS, 16B per lane. LDS base must be wave-uniform; HW adds lane*16.
__device__ __forceinline__ void cp16(void* lds, const void* g) {
    __builtin_amdgcn_global_load_lds(
        (const __attribute__((address_space(1))) void*)g,
        (__attribute__((address_space(3))) void*)lds, 16, 0, 0);
}

__device__ __forceinline__ float fexp2(float x) {
    float r; asm("v_exp_f32 %0, %1" : "=v"(r) : "v"(x)); return r;
}
__device__ __forceinline__ unsigned int pk_bf16(float a, float b) {
    unsigned int r; asm("v_cvt_pk_bf16_f32 %0, %1, %2" : "=v"(r) : "v"(a), "v"(b)); return r;
}

__device__ __forceinline__ void plswap(unsigned int& a, unsigned int& b) {
#if __has_builtin(__builtin_amdgcn_permlane32_swap)
    auto r = __builtin_amdgcn_permlane32_swap(a, b, false, false);
    a = r[0]; b = r[1];
#else
    unsigned int sa = __shfl_xor((int)a, 32), sb = __shfl_xor((int)b, 32);
    bool hi = (threadIdx.x & 63) >= 32;
    unsigned int na = hi ? sb : a, nb = hi ? b : sa;
    a = na; b = nb;
#endif
}
__device__ __forceinline__ float partner32(float x, int hi) {
#if __has_builtin(__builtin_amdgcn_permlane32_swap)
    unsigned int u = __float_as_uint(x);
    auto r = __builtin_amdgcn_permlane32_swap(u, u, false, false);
    return __uint_as_float(hi ? r[0] : r[1]);
#else
    return __shfl_xor(x, 32);
#endif
}

#define QSCALE 0.18033688011112043f   // 0.125 * log2(e)

// ---------------------------------------------------------------------------
// Combined conversion kernel, slim grid (2240,1,3):
//   x < 2048 : z=0/1/2 -> q/k/v f32 -> bf16, grid-stride
//   x >= 2048: weight tile widx = z*192 + (x-2048) in [0,576):
//              zz = widx/144 selects wq/wk/wv/wo; tile = widx%144.
//              f32 [k][n] -> bf16 transposed [n][k].
// ---------------------------------------------------------------------------
__global__ __launch_bounds__(256) void conv_all(
    const float* __restrict__ x0, const float* __restrict__ x1, const float* __restrict__ x2,
    ushort* __restrict__ o0, ushort* __restrict__ o1, ushort* __restrict__ o2,
    const float* __restrict__ w0, const float* __restrict__ w1,
    const float* __restrict__ w2, const float* __restrict__ w3,
    ushort* __restrict__ t0, ushort* __restrict__ t1,
    ushort* __restrict__ t2, ushort* __restrict__ t3)
{
    const int z = blockIdx.z;
    if (blockIdx.x < 2048) {
        const float* x = z == 0 ? x0 : (z == 1 ? x1 : x2);
        ushort* o = z == 0 ? o0 : (z == 1 ? o1 : o2);
        const int total4 = MM * DD / 4;
        for (int i = blockIdx.x * 256 + threadIdx.x; i < total4; i += 2048 * 256) {
            float4 v = *(const float4*)&x[i * 4];
            ushort4 r;
            r.x = f2bf(v.x); r.y = f2bf(v.y); r.z = f2bf(v.z); r.w = f2bf(v.w);
            *(ushort4*)&o[i * 4] = r;
        }
    } else {
        __shared__ ushort tile[64][72];
        const int widx = z * 192 + (blockIdx.x - 2048);   // 0..575
        const int zz = widx / 144;
        const int tl = widx % 144;
        const float* w = zz == 0 ? w0 : zz == 1 ? w1 : zz == 2 ? w2 : w3;
        ushort* o = zz == 0 ? t0 : zz == 1 ? t1 : zz == 2 ? t2 : t3;
        const int n0 = (tl % (DD / 64)) * 64;
        const int k0 = (tl / (DD / 64)) * 64;
        #pragma unroll
        for (int it = 0; it < 4; ++it) {
            int e = (threadIdx.x + it * 256) * 4;
            int r = e >> 6, c = e & 63;
            float4 v = *(const float4*)&w[(size_t)(k0 + r) * DD + n0 + c];
            tile[c + 0][r] = f2bf(v.x);
            tile[c + 1][r] = f2bf(v.y);
            tile[c + 2][r] = f2bf(v.z);
            tile[c + 3][r] = f2bf(v.w);
        }
        __syncthreads();
        #pragma unroll
        for (int it = 0; it < 4; ++it) {
            int e = (threadIdx.x + it * 256) * 4;
            int nr = e >> 6, kc = e & 63;
            ushort4 r4;
            r4.x = tile[nr][kc + 0];
            r4.y = tile[nr][kc + 1];
            r4.z = tile[nr][kc + 2];
            r4.w = tile[nr][kc + 3];
            *(ushort4*)&o[(size_t)(n0 + nr) * DD + k0 + kc] = r4;
        }
    }
}

// ---------------------------------------------------------------------------
// MFMA GEMM: A[M][K=768] bf16 x WT[N][K] bf16. Tile TM x TN, 4 waves 2x2,
// BK=64 (128B rows), XOR-swizzled LDS (byte ^= (row&7)<<4), coalesced
// in-row pre-swizzled cp16 source. 2-buffer __syncthreads loop.
// 1D grid, XCD-chunked task mapping (T1): p -> task (p%8)*(G/8) + p/8, so
// the nx x-tiles sharing an A-panel land on one XCD's L2.
// MODE 0: rope>=0 -> bf16 head layout [B,H,T,ND] + bias (+fused RoPE);
//         rope==-1 -> bf16 transposed layout [B][n][T] + bias (V^T direct)
// MODE 1: f32 flat [M][N], no bias.
// ---------------------------------------------------------------------------
struct GArgs { const ushort* x; const ushort* wt; const float* bias; void* out;
               const float* cT; const float* sT; int rope; };

template<int MODE, int TM, int TN>
__global__ __launch_bounds__(256) void gemm_bf16(GArgs a0, GArgs a1, GArgs a2,
                                                 int nx, int ny)
{
    constexpr int WM = TM / 2, WN = TN / 2;
    constexpr int MF = WM / 16, NF = WN / 16;
    constexpr int ABYTES = TM * 128;          // A region bytes (128B per row)
    constexpr int BUFB = (TM + TN) * 128;     // bytes per buffer (A then B)
    constexpr int NPASS = BUFB / 4096;        // staging passes (4KB per pass)
    constexpr int NK = DD / 64;               // 12 K-iterations
    __shared__ __align__(16) ushort S[2][BUFB / 2];
    const int tid = threadIdx.x;
    const int w = tid >> 6, l = tid & 63;
    const int wr = w >> 1, wc = w & 1;

    // XCD-chunked mapping (grid %8 == 0)
    const int per = gridDim.x >> 3;
    const int p = blockIdx.x;
    const int task = (p & 7) * per + (p >> 3);
    const int bx = task % nx;
    const int by = (task / nx) % ny;
    const int bz = task / (nx * ny);
    GArgs ga = (bz == 0) ? a0 : (bz == 1 ? a1 : a2);
    const int n0 = bx * TN, m0 = by * TM;

    f32x4 acc[MF][NF] = {};

    auto stage = [&](int buf, int k0) {
        #pragma unroll
        for (int it = 0; it < NPASS; ++it) {
            const int ob = it * 4096 + w * 1024;       // wave-uniform chunk base
            const int o = ob + l * 16;
            if (ob < ABYTES) {
                const int row = o >> 7, inner = o & 127;
                cp16((char*)&S[buf][0] + ob,
                     (const char*)ga.x + (size_t)(m0 + row) * (DD * 2) + k0 * 2 +
                     (inner ^ ((row & 7) << 4)));
            } else {
                const int o2 = o - ABYTES;
                const int row = o2 >> 7, inner = o2 & 127;
                cp16((char*)&S[buf][0] + ob,
                     (const char*)ga.wt + (size_t)(n0 + row) * (DD * 2) + k0 * 2 +
                     (inner ^ ((row & 7) << 4)));
            }
        }
    };

    stage(0, 0);
    __syncthreads();
    const int lq = l >> 4, lr = l & 15;
    for (int t = 0; t < NK; ++t) {
        const int cur = t & 1;
        if (t + 1 < NK) stage(cur ^ 1, (t + 1) * 64);
        const char* ab = (const char*)&S[cur][0];
        #pragma unroll
        for (int kc = 0; kc < 2; ++kc) {
            const int kb = kc * 64 + lq * 16;
            bf16x8 af[MF], bfr[NF];
            #pragma unroll
            for (int i = 0; i < MF; ++i) {
                const int row = WM * wr + 16 * i + lr;
                af[i] = *(const bf16x8*)(ab + row * 128 + (kb ^ ((row & 7) << 4)));
            }
            #pragma unroll
            for (int j = 0; j < NF; ++j) {
                const int row = WN * wc + 16 * j + lr;
                bfr[j] = *(const bf16x8*)(ab + ABYTES + row * 128 + (kb ^ ((row & 7) << 4)));
            }
            __builtin_amdgcn_s_setprio(1);
            #pragma unroll
            for (int i = 0; i < MF; ++i)
                #pragma unroll
                for (int j = 0; j < NF; ++j)
                    acc[i][j] = __builtin_amdgcn_mfma_f32_16x16x32_bf16(af[i], bfr[j], acc[i][j], 0, 0, 0);
            __builtin_amdgcn_s_setprio(0);
        }
        __syncthreads();
    }

    if (MODE == 0 && ga.rope == -1) {
        // ---- transposed epilogue (V^T): out[b][n][t], n = h*64+d ----
        ushort* tl = (ushort*)&S[0][0];   // [TN][TM + 8] padded bf16 tile
        #pragma unroll
        for (int i = 0; i < MF; ++i) {
            #pragma unroll
            for (int j = 0; j < NF; ++j) {
                #pragma unroll
                for (int r = 0; r < 4; ++r) {
                    const int ml = WM * wr + 16 * i + (l >> 4) * 4 + r;
                    const int nl = WN * wc + 16 * j + (l & 15);
                    tl[nl * (TM + 8) + ml] = f2bf(acc[i][j][r] + ga.bias[n0 + nl]);
                }
            }
        }
        __syncthreads();
        const int b = m0 >> 11, t0b = m0 & 2047;
        ushort* base = (ushort*)ga.out + ((size_t)(b * DD + n0)) * TT + t0b;
        #pragma unroll
        for (int it = 0; it < TM * TN / (256 * 8); ++it) {
            const int slot = tid + it * 256;
            const int d = slot / (TM / 8), c = (slot % (TM / 8)) * 8;
            bf16x8 v = *(const bf16x8*)&tl[d * (TM + 8) + c];
            *(bf16x8*)&base[(size_t)d * TT + c] = v;
        }
        return;
    }

    #pragma unroll
    for (int i = 0; i < MF; ++i) {
        #pragma unroll
        for (int j = 0; j < NF; ++j) {
            #pragma unroll
            for (int r = 0; r < 4; ++r) {
                const int m = m0 + WM * wr + 16 * i + (l >> 4) * 4 + r;
                const int n = n0 + WN * wc + 16 * j + (l & 15);
                float v = acc[i][j][r];
                if (MODE == 0) {
                    v += ga.bias[n];
                    const int tt = m & 2047;
                    if (ga.rope > 0) {
                        const int d = n & 63;
                        const float c = ga.cT[tt * 32 + (d >> 1)];
                        const float s = ga.sT[tt * 32 + (d >> 1)];
                        const float pv = __shfl_xor(v, 1);
                        v = (n & 1) ? (pv * s + v * c) : (v * c - pv * s);
                        if (ga.rope == 2) v *= QSCALE;
                    }
                    const int b = m >> 11;
                    const int h = n >> 6, d = n & 63;
                    ((ushort*)ga.out)[((size_t)(b * HH + h) * TT + tt) * ND + d] = f2bf(v);
                } else {
                    ((float*)ga.out)[(size_t)m * DD + n] = v;
                }
            }
        }
    }
}

// ---------------------------------------------------------------------------
// MFMA flash attention, 32x32 swapped-operand + in-block KV-split + balanced
// static schedule. 1D grid of NTASK=384 tasks (16 qblk x 24 bh).
// ---------------------------------------------------------------------------
#define NQB (TT/128)        // 16
#define NBH (BB*HH)         // 24
#define NTASK (NQB*NBH)     // 384
#define NCU 256

__global__ __launch_bounds__(512) void attn_mfma4(const ushort* __restrict__ Qh,
                                                  const ushort* __restrict__ Kh,
                                                  const ushort* __restrict__ VhT,
                                                  ushort* __restrict__ Op)
{
    __shared__ __align__(16) ushort Ks[2][2][4096];   // [kvhalf][buf][64kv x 64d] swizzled
    __shared__ __align__(16) ushort Vs[2][2][4096];   // [kvhalf][buf][64d x 64kv] swizzled
    const int tid = threadIdx.x;
    const int w = tid >> 6, l = tid & 63;
    const int lq = l & 31, hi = l >> 5;
    const int qs = w & 3;                 // q subgroup (32 rows)
    const int kvh = w >> 2;               // kv half

    const int n = blockIdx.x;
    const int r_ = (n < NCU) ? n : (NTASK - 1 + NCU - n);
    const int qblk = (NQB - 1) - r_ / NBH;
    const int bh = r_ % NBH;

    const int q0 = qblk * 128;
    const int q0w = q0 + qs * 32;
    const int qg = q0w + lq;              // this lane's q row
    const int ntH = qblk + 1;             // kv tiles per half
    const int kvbase = kvh * ntH * 64;

    const ushort* Qg = Qh + ((size_t)bh * TT + q0w) * ND;
    const ushort* Kg = Kh + (size_t)bh * TT * ND;
    const ushort* Vg = VhT + (size_t)bh * ND * TT;

    // Q fragments from global (B-operand: lane holds q row lq, d = ks*16+hi*8+e)
    bf16x8 qf[4];
    #pragma unroll
    for (int ks = 0; ks < 4; ++ks)
        qf[ks] = *(const bf16x8*)((const char*)Qg + lq * 128 + ks * 32 + hi * 16);

    auto stageKV = [&](int buf, int kv0) {
        #pragma unroll
        for (int it = 0; it < 2; ++it) {
            int o = it * 4096 + qs * 1024 + l * 16;
            int row = o >> 7, inner = o & 127;
            int swz = inner ^ ((row & 7) << 4);
            cp16((char*)&Ks[kvh][buf][0] + it * 4096 + qs * 1024,
                 (const char*)Kg + (size_t)(kv0 + row) * 128 + swz);
            cp16((char*)&Vs[kvh][buf][0] + it * 4096 + qs * 1024,
                 (const char*)Vg + (size_t)row * (TT * 2) + kv0 * 2 + swz);
        }
    };

    float m = -1e30f, lsum = 0.f;
    f32x16 o0 = {}, o1 = {};

    stageKV(0, kvbase);
    __syncthreads();
    for (int t = 0; t < ntH; ++t) {
        const int cur = t & 1;
        if (t + 1 < ntH) stageKV(cur ^ 1, kvbase + (t + 1) * 64);
        const char* kb = (const char*)&Ks[kvh][cur][0];
        const char* vb = (const char*)&Vs[kvh][cur][0];
        const int kvt = kvbase + t * 64;

        if (kvt <= q0w + 31) {
            const bool have1 = (kvt + 32 <= q0w + 31);   // wave-uniform

            // S^T[kv][q]: both 32-kv subtiles
            f32x16 st0 = {}, st1 = {};
            __builtin_amdgcn_s_setprio(1);
            #pragma unroll
            for (int ks = 0; ks < 4; ++ks) {
                bf16x8 kf = *(const bf16x8*)(kb + lq * 128 +
                                             ((ks * 32 + hi * 16) ^ ((lq & 7) << 4)));
                st0 = __builtin_amdgcn_mfma_f32_32x32x16_bf16(kf, qf[ks], st0, 0, 0, 0);
            }
            if (have1) {
                #pragma unroll
                for (int ks = 0; ks < 4; ++ks) {
                    bf16x8 kf = *(const bf16x8*)(kb + (32 + lq) * 128 +
                                                 ((ks * 32 + hi * 16) ^ ((lq & 7) << 4)));
                    st1 = __builtin_amdgcn_mfma_f32_32x32x16_bf16(kf, qf[ks], st1, 0, 0, 0);
                }
            }
            __builtin_amdgcn_s_setprio(0);

            // causal mask + tile max over all 64 kv (one chain per tile)
            float tm = -1e30f;
            if (kvt + 31 > q0w) {
                #pragma unroll
                for (int r = 0; r < 16; ++r) {
                    const int kvg = kvt + (r & 3) + 8 * (r >> 2) + 4 * hi;
                    float x = (kvg <= qg) ? st0[r] : -1e30f;
                    st0[r] = x;
                    tm = fmaxf(tm, x);
                }
            } else {
                #pragma unroll
                for (int r = 0; r < 16; ++r) tm = fmaxf(tm, st0[r]);
            }
            if (have1) {
                if (kvt + 63 > q0w) {
                    #pragma unroll
                    for (int r = 0; r < 16; ++r) {
                        const int kvg = kvt + 32 + (r & 3) + 8 * (r >> 2) + 4 * hi;
                        float x = (kvg <= qg) ? st1[r] : -1e30f;
                        st1[r] = x;
                        tm = fmaxf(tm, x);
                    }
                } else {
                    #pragma unroll
                    for (int r = 0; r < 16; ++r) tm = fmaxf(tm, st1[r]);
                }
            }
            tm = fmaxf(tm, partner32(tm, hi));

            // defer-max (T13)
            const bool defer = __all(tm <= m + 11.5f);
            float alpha = 1.f;
            if (!defer) {
                const float nm = fmaxf(m, tm);
                alpha = fexp2(m - nm);
                m = nm;
            }

            // P = exp2(S - m), pack to bf16 pairs, tree rowsum
            float ps[16];
            unsigned int pkA[8], pkB[8];
            #pragma unroll
            for (int i = 0; i < 8; ++i) {
                const float p0 = fexp2(st0[2 * i + 0] - m);
                const float p1 = fexp2(st0[2 * i + 1] - m);
                pkA[i] = pk_bf16(p0, p1);
                ps[i] = p0 + p1;
            }
            if (have1) {
                #pragma unroll
                for (int i = 0; i < 8; ++i) {
                    const float p0 = fexp2(st1[2 * i + 0] - m);
                    const float p1 = fexp2(st1[2 * i + 1] - m);
                    pkB[i] = pk_bf16(p0, p1);
                    ps[8 + i] = p0 + p1;
                }
            } else {
                #pragma unroll
                for (int i = 0; i < 8; ++i) { pkB[i] = 0; ps[8 + i] = 0.f; }
            }
            const float t0s = (ps[0] + ps[1]) + (ps[2] + ps[3]);
            const float t1s = (ps[4] + ps[5]) + (ps[6] + ps[7]);
            const float t2s = (ps[8] + ps[9]) + (ps[10] + ps[11]);
            const float t3s = (ps[12] + ps[13]) + (ps[14] + ps[15]);
            float rs = (t0s + t1s) + (t2s + t3s);
            rs += partner32(rs, hi);
            lsum = lsum * alpha + rs;

            // rearrange into PV B-fragments
            plswap(pkA[0], pkA[2]); plswap(pkA[1], pkA[3]);
            plswap(pkA[4], pkA[6]); plswap(pkA[5], pkA[7]);
            if (have1) {
                plswap(pkB[0], pkB[2]); plswap(pkB[1], pkB[3]);
                plswap(pkB[4], pkB[6]); plswap(pkB[5], pkB[7]);
            }
            union { unsigned int u[4]; bf16x8 v; } pa0, pa1, pa2, pa3;
            pa0.u[0] = pkA[0]; pa0.u[1] = pkA[1]; pa0.u[2] = pkA[2]; pa0.u[3] = pkA[3];
            pa1.u[0] = pkA[4]; pa1.u[1] = pkA[5]; pa1.u[2] = pkA[6]; pa1.u[3] = pkA[7];
            pa2.u[0] = pkB[0]; pa2.u[1] = pkB[1]; pa2.u[2] = pkB[2]; pa2.u[3] = pkB[3];
            pa3.u[0] = pkB[4]; pa3.u[1] = pkB[5]; pa3.u[2] = pkB[6]; pa3.u[3] = pkB[7];

            if (!defer) {
                #pragma unroll
                for (int r = 0; r < 16; ++r) { o0[r] *= alpha; o1[r] *= alpha; }
            }

            // O^T += V^T * P
            __builtin_amdgcn_s_setprio(1);
            #pragma unroll
            for (int sl = 0; sl < 2; ++sl) {
                const bf16x8 pf = sl == 0 ? pa0.v : pa1.v;
                const int cb = sl * 32 + hi * 16;
                bf16x8 va = *(const bf16x8*)(vb + lq * 128 + (cb ^ ((lq & 7) << 4)));
                bf16x8 vc = *(const bf16x8*)(vb + (lq + 32) * 128 + (cb ^ ((lq & 7) << 4)));
                o0 = __builtin_amdgcn_mfma_f32_32x32x16_bf16(va, pf, o0, 0, 0, 0);
                o1 = __builtin_amdgcn_mfma_f32_32x32x16_bf16(vc, pf, o1, 0, 0, 0);
            }
            if (have1) {
                #pragma unroll
                for (int sl = 0; sl < 2; ++sl) {
                    const bf16x8 pf = sl == 0 ? pa2.v : pa3.v;
                    const int cb = 64 + sl * 32 + hi * 16;
                    bf16x8 va = *(const bf16x8*)(vb + lq * 128 + (cb ^ ((lq & 7) << 4)));
                    bf16x8 vc = *(const bf16x8*)(vb + (lq + 32) * 128 + (cb ^ ((lq & 7) << 4)));
                    o0 = __builtin_amdgcn_mfma_f32_32x32x16_bf16(va, pf, o0, 0, 0, 0);
                    o1 = __builtin_amdgcn_mfma_f32_32x32x16_bf16(vc, pf, o1, 0, 0, 0);
                }
            }
            __builtin_amdgcn_s_setprio(0);
        }
        __syncthreads();
    }

    // ---- merge kv halves through LDS ----
    float* xO  = (float*)&Ks[0][0][0];    // 4 regions x 8KB = 32KB ([reg][lane])
    float* xML = (float*)&Vs[0][0][0];    // m,l per q-sub
    if (kvh == 1) {
        float* dst = xO + qs * 2048;
        #pragma unroll
        for (int r = 0; r < 16; ++r) {
            dst[r * 64 + l] = o0[r];
            dst[(r + 16) * 64 + l] = o1[r];
        }
        if (hi == 0) { xML[qs * 64 + lq] = m; xML[qs * 64 + 32 + lq] = lsum; }
    }
    __syncthreads();
    if (kvh == 0) {
        const float* src = xO + qs * 2048;
        const float m1 = xML[qs * 64 + lq];
        const float l1 = xML[qs * 64 + 32 + lq];
        const float ms = fmaxf(m, m1);
        const float a0 = fexp2(m - ms), a1 = fexp2(m1 - ms);
        const float inv = 1.0f / (lsum * a0 + l1 * a1);
        const int b = bh / HH, h = bh % HH;
        ushort* dst = Op + ((size_t)(b * TT + qg)) * DD + h * ND;
        #pragma unroll
        for (int g = 0; g < 4; ++g) {
            ushort4 w0, w1;
            w0.x = f2bf((o0[4 * g + 0] * a0 + src[(4 * g + 0) * 64 + l] * a1) * inv);
            w0.y = f2bf((o0[4 * g + 1] * a0 + src[(4 * g + 1) * 64 + l] * a1) * inv);
            w0.z = f2bf((o0[4 * g + 2] * a0 + src[(4 * g + 2) * 64 + l] * a1) * inv);
            w0.w = f2bf((o0[4 * g + 3] * a0 + src[(4 * g + 3) * 64 + l] * a1) * inv);
            *(ushort4*)&dst[8 * g + 4 * hi] = w0;
            w1.x = f2bf((o1[4 * g + 0] * a0 + src[(16 + 4 * g + 0) * 64 + l] * a1) * inv);
            w1.y = f2bf((o1[4 * g + 1] * a0 + src[(16 + 4 * g + 1) * 64 + l] * a1) * inv);
            w1.z = f2bf((o1[4 * g + 2] * a0 + src[(16 + 4 * g + 2) * 64 + l] * a1) * inv);
            w1.w = f2bf((o1[4 * g + 3] * a0 + src[(16 + 4 * g + 3) * 64 + l] * a1) * inv);
            *(ushort4*)&dst[32 + 8 * g + 4 * hi] = w1;
        }
    }
}

// ---------------------------------------------------------------------------
extern "C" void kernel_launch(void* const* d_in, const int* in_sizes, int n_in,
                              void* d_out, int out_size, void* d_ws, size_t ws_size,
                              hipStream_t stream)
{
    const float* q  = (const float*)d_in[0];
    const float* k  = (const float*)d_in[1];
    const float* v  = (const float*)d_in[2];
    const float* wq = (const float*)d_in[4];
    const float* bq = (const float*)d_in[5];
    const float* wk = (const float*)d_in[6];
    const float* bk = (const float*)d_in[7];
    const float* wv = (const float*)d_in[8];
    const float* bv = (const float*)d_in[9];
    const float* wo = (const float*)d_in[10];
    const float* fc = (const float*)d_in[11];
    const float* fs = (const float*)d_in[12];
    float* out = (float*)d_out;

    ushort* qB  = (ushort*)d_ws;           // [M][D] bf16
    ushort* kB  = qB  + (size_t)MM * DD;
    ushort* vB  = kB  + (size_t)MM * DD;
    ushort* wqT = vB  + (size_t)MM * DD;   // [n][k] bf16
    ushort* wkT = wqT + (size_t)DD * DD;
    ushort* wvT = wkT + (size_t)DD * DD;
    ushort* woT = wvT + (size_t)DD * DD;
    ushort* Qh  = woT + (size_t)DD * DD;   // [B,H,T,ND] bf16
    ushort* Kh  = Qh  + (size_t)MM * DD;
    ushort* VhT = Kh  + (size_t)MM * DD;   // [B,H,ND,T] bf16 (direct from V-GEMM)
    ushort* Op  = qB;                      // alias: qB dead after QKV GEMM

    conv_all<<<dim3(2240, 1, 3), 256, 0, stream>>>(q, k, v, qB, kB, vB,
                                                   wq, wk, wv, wo, wqT, wkT, wvT, woT);

    GArgs aq{qB, wqT, bq, (void*)Qh, fc, fs, 2};
    GArgs ak{kB, wkT, bk, (void*)Kh, fc, fs, 1};
    GArgs av{vB, wvT, bv, (void*)VhT, nullptr, nullptr, -1};   // V^T direct
    // 1D grid 12*32*3 = 1152 (%8==0), XCD-chunked
    gemm_bf16<0, 128, 64><<<dim3(1152), 256, 0, stream>>>(aq, ak, av, DD / 64, MM / 128);

    attn_mfma4<<<dim3(NTASK), 512, 0, stream>>>(Qh, Kh, VhT, Op);

    GArgs ao{Op, woT, nullptr, (void*)out, nullptr, nullptr, 0};
    // 1D grid 12*64 = 768 (%8==0), XCD-chunked
    gemm_bf16<1, 64, 64><<<dim3(768), 256, 0, stream>>>(ao, ao, ao, DD / 64, MM / 64);
}